// Round 5
// baseline (672.654 us; speedup 1.0000x reference)
//
#include <hip/hip_runtime.h>

#define TSTEPS 1023
#define GAMMA  (0.01f / 32.0f)   // LR * dL/dy scale: 2/(64*2) folded
#define EPSV   1e-5f

// workspace layout (float offsets)
#define WS_HS 0       // 64*64 hs table
#define WS_G  4096    // 64*64 gram
#define WS_Z0 8192    // 64*16 initial Ztilde = hs@w1 + b1

typedef float v2f __attribute__((ext_vector_type(2)));
typedef unsigned int v2u __attribute__((ext_vector_type(2)));

__device__ __forceinline__ float rdlane(float v, int lane) {
    return __int_as_float(__builtin_amdgcn_readlane(__float_as_int(v), lane));
}
template<int CTRL>
__device__ __forceinline__ float dppmov(float x) {
    return __int_as_float(__builtin_amdgcn_update_dpp(0, __float_as_int(x), CTRL, 0xF, 0xF, true));
}
// sum over {l, l^16}: both outputs of a self permlane16_swap are the two row-halves
__device__ __forceinline__ float sum_x16(float x) {
#if __has_builtin(__builtin_amdgcn_permlane16_swap)
    v2u r = __builtin_amdgcn_permlane16_swap(__float_as_uint(x), __float_as_uint(x), false, false);
    return __uint_as_float(r[0]) + __uint_as_float(r[1]);
#else
    float a = x, b = x;
    asm("v_permlane16_swap_b32 %0, %1" : "+v"(a), "+v"(b));
    return a + b;
#endif
}
// sum over {l, l^32}
__device__ __forceinline__ float sum_x32(float x) {
#if __has_builtin(__builtin_amdgcn_permlane32_swap)
    v2u r = __builtin_amdgcn_permlane32_swap(__float_as_uint(x), __float_as_uint(x), false, false);
    return __uint_as_float(r[0]) + __uint_as_float(r[1]);
#else
    float a = x, b = x;
    asm("v_permlane32_swap_b32 %0, %1" : "+v"(a), "+v"(b));
    return a + b;
#endif
}

// ---------------- kernel A: hs table (per-token embed->FFN->LN) ----------------
__global__ void hs_kernel(const float* __restrict__ embed,
                          const float* __restrict__ ffw1, const float* __restrict__ ffb1,
                          const float* __restrict__ ffw2, const float* __restrict__ ffb2,
                          const float* __restrict__ lng,  const float* __restrict__ lnb,
                          float* __restrict__ ws) {
    __shared__ float e[64];
    __shared__ float a1[128];
    int w = blockIdx.x;
    int tid = threadIdx.x;
    if (tid < 64) e[tid] = embed[w * 64 + tid];
    __syncthreads();
    float z1 = ffb1[tid];
    for (int x = 0; x < 64; ++x) z1 += e[x] * ffw1[x * 128 + tid];
    a1[tid] = fmaxf(z1, 0.0f);
    __syncthreads();
    if (tid < 64) {
        float f = ffb2[tid];
        for (int i = 0; i < 128; ++i) f += a1[i] * ffw2[i * 64 + tid];
        float hv = e[tid] + f;
        float s = hv;
#pragma unroll
        for (int m = 32; m >= 1; m >>= 1) s += __shfl_xor(s, m);
        float mu = s * (1.0f / 64.0f);
        float dv = hv - mu;
        float vs = dv * dv;
#pragma unroll
        for (int m = 32; m >= 1; m >>= 1) vs += __shfl_xor(vs, m);
        float rstd = 1.0f / sqrtf(vs * (1.0f / 64.0f) + EPSV);
        ws[WS_HS + w * 64 + tid] = dv * rstd * lng[tid] + lnb[tid];
    }
}

// ---------------- kernel B: Gram matrix + Ztilde0 ----------------
__global__ void gz_kernel(const float* __restrict__ w1, const float* __restrict__ b1,
                          float* __restrict__ ws) {
    __shared__ float row[64];
    int w = blockIdx.x, tid = threadIdx.x;
    row[tid] = ws[WS_HS + w * 64 + tid];
    __syncthreads();
    float g = 0.0f;
    for (int x = 0; x < 64; ++x) g += row[x] * ws[WS_HS + tid * 64 + x];
    ws[WS_G + w * 64 + tid] = g;
    if (tid < 16) {
        float z = b1[tid];
        for (int x = 0; x < 64; ++x) z += row[x] * w1[x * 16 + tid];
        ws[WS_Z0 + w * 16 + tid] = z;
    }
}

// scalar view of packed p
#define PV(arr, j) (((j) & 1) ? arr[(j) >> 1].y : arr[(j) >> 1].x)

// ---------------- main kernel: per-batch sequential TTT scan ----------------
// one wave per batch. lane h owns W2[:,h], b2_h, Ztilde row h (regs + LDS
// mirror). Token pairs prefetched 2 iters ahead in regs -> all per-iter DS
// reads issue at iter top with reg addresses. Reduction is 100% VALU:
// quad_perm folds (xor1,xor2) -> row_ror:4/8 orbit sums -> permlane16/32_swap
// pair sums -> readlane broadcast. No on-chain DS anywhere in the loop.
__launch_bounds__(64, 1)
__global__ void ttt_kernel(const int* __restrict__ seq,
                           const float* __restrict__ w2, const float* __restrict__ b2i,
                           const float* __restrict__ outw, const float* __restrict__ outb,
                           const float* __restrict__ ws, float* __restrict__ out) {
    __shared__ float hs[64 * 64];
    __shared__ float G[64 * 64];
    __shared__ int   sq[2048];
    __shared__ __align__(16) float Z[64 * 20];   // row stride 20: conflict-free b128
    __shared__ float ctxbuf[64];

    const int b    = blockIdx.x;
    const int lane = threadIdx.x;

    {   // vectorized staging
        float4*       hv = (float4*)hs;
        const float4* sv = (const float4*)(ws + WS_HS);
#pragma unroll
        for (int m = 0; m < 16; ++m) hv[m * 64 + lane] = sv[m * 64 + lane];
        float4*       gv = (float4*)G;
        const float4* gs = (const float4*)(ws + WS_G);
#pragma unroll
        for (int m = 0; m < 16; ++m) gv[m * 64 + lane] = gs[m * 64 + lane];
        int4*       qv = (int4*)sq;
        const int4* qs = (const int4*)(seq + b * 2048);
#pragma unroll
        for (int m = 0; m < 8; ++m) qv[m * 64 + lane] = qs[m * 64 + lane];
    }

    v2f W2p[8], Zrp[8], z2[8];
#pragma unroll
    for (int i = 0; i < 8; ++i) {
        v2f w;
        w.x = w2[(2 * i) * 64 + lane];
        w.y = w2[(2 * i + 1) * 64 + lane];
        W2p[i] = w;
    }
    float b2v = b2i[lane];
    {
        const float4* z0 = (const float4*)(ws + WS_Z0 + lane * 16);
        float4 u0 = z0[0], u1 = z0[1], u2 = z0[2], u3 = z0[3];
        Zrp[0] = {u0.x, u0.y}; Zrp[1] = {u0.z, u0.w};
        Zrp[2] = {u1.x, u1.y}; Zrp[3] = {u1.z, u1.w};
        Zrp[4] = {u2.x, u2.y}; Zrp[5] = {u2.z, u2.w};
        Zrp[6] = {u3.x, u3.y}; Zrp[7] = {u3.z, u3.w};
        float4* zr = (float4*)(Z + lane * 20);
        zr[0] = u0; zr[1] = u1; zr[2] = u2; zr[3] = u3;
    }
    __syncthreads();

    int tk = sq[0];
    {
        const float4* zp = (const float4*)(Z + tk * 20);
        float4 u0 = zp[0], u1 = zp[1], u2 = zp[2], u3 = zp[3];
        z2[0] = {u0.x, u0.y}; z2[1] = {u0.z, u0.w};
        z2[2] = {u1.x, u1.y}; z2[3] = {u1.z, u1.w};
        z2[4] = {u2.x, u2.y}; z2[5] = {u2.z, u2.w};
        z2[6] = {u3.x, u3.y}; z2[7] = {u3.z, u3.w};
    }
    float vv = hs[sq[1] * 64 + lane];

    // token-pair prefetch pipeline: pairT for iter t, pairT1 for iter t+1
    int2 pairT  = *(const int2*)(sq + 2);   // base(0)
    int2 pairT1 = *(const int2*)(sq + 4);   // base(1)

    const bool bl0 = (lane & 1) != 0;
    const bool bl1 = (lane & 2) != 0;

#pragma unroll 2
    for (int t = 0; t < TSTEPS; ++t) {
        const bool last = (t == TSTEPS - 1);
        const int  tkn  = last ? pairT.y : pairT.x;   // last iter: query token sq[2047]
        const int  tvn  = pairT.y;

        // ---- all DS reads issue here with register addresses (consumed late) ----
        const float4* zp = (const float4*)(Z + tkn * 20);   // Ztilde_t[tkn] (pre-writeback of this iter)
        const float4 e0 = zp[0], e1 = zp[1], e2 = zp[2], e3 = zp[3];
        const float vnext = hs[tvn * 64 + lane];
        const float cr = GAMMA * G[tk * 64 + lane] + GAMMA;  // gamma*(G[lane][tk]+1)
        const float cz = GAMMA * G[tk * 64 + tkn] + GAMMA;   // gamma*(G[tkn][tk]+1)
        const int   lbase = (t < TSTEPS - 3) ? (2 * t + 6) : 2046;
        const int2  pairT2 = *(const int2*)(sq + lbase);     // pair for iter t+2

        // ---- forward (packed) ----
        const v2f zero2 = {0.0f, 0.0f};
        v2f a2[8];
#pragma unroll
        for (int i = 0; i < 8; ++i) a2[i] = __builtin_elementwise_max(z2[i], zero2);
        v2f acc0 = a2[0] * W2p[0] + a2[1] * W2p[1];
        v2f acc1 = a2[2] * W2p[2] + a2[3] * W2p[3];
        v2f acc2 = a2[4] * W2p[4] + a2[5] * W2p[5];
        v2f acc3 = a2[6] * W2p[6] + a2[7] * W2p[7];
        v2f accv = (acc0 + acc1) + (acc2 + acc3);
        const float y = b2v + accv.x + accv.y;
        const float d = y - vv;

        // ---- p (pre-update W2) + local W2/b2 update (packed) ----
        const v2f d2  = {d, d};
        v2f p2[8];
#pragma unroll
        for (int i = 0; i < 8; ++i) p2[i] = W2p[i] * d2;
        const float sd = GAMMA * d;
        const v2f sd2 = {sd, sd};
        b2v -= sd;
#pragma unroll
        for (int i = 0; i < 8; ++i) W2p[i] = W2p[i] - sd2 * a2[i];

        // ---- reduction (all-VALU) ----
        // S1: fold (j, j+8) over xor1: orbit-sum both, select by b0
        float q[8];
#pragma unroll
        for (int j = 0; j < 8; ++j) {
            const float A = PV(p2, j)     + dppmov<0xB1>(PV(p2, j));
            const float B = PV(p2, j + 8) + dppmov<0xB1>(PV(p2, j + 8));
            q[j] = bl0 ? B : A;
        }
        // S2: fold (j, j+4) over xor2
        float r[4];
#pragma unroll
        for (int j = 0; j < 4; ++j) {
            const float A = q[j]     + dppmov<0x4E>(q[j]);
            const float B = q[j + 4] + dppmov<0x4E>(q[j + 4]);
            r[j] = bl1 ? B : A;
        }
        // S3: within-row stride-4 orbit sums (row_ror 4, 8)
        // S4: cross-row pair sums via permlane16/32_swap (VALU)
        float tot[4];
#pragma unroll
        for (int j = 0; j < 4; ++j) {
            float x = r[j] + dppmov<0x124>(r[j]);
            x = x + dppmov<0x128>(x);
            x = sum_x16(x);
            tot[j] = sum_x32(x);
        }
        // da[m] = tot[m&3] at lane (b0 = m>>3, b1 = (m>>2)&1)

        // ---- broadcast + apply ----
        float dz[16];
#pragma unroll
        for (int m = 0; m < 16; ++m) {
            const float da = rdlane(tot[m & 3], ((m >> 3) & 1) + 2 * ((m >> 2) & 1));
            dz[m] = (PV(a2, m) > 0.0f) ? da : 0.0f;   // a>0 <=> z>0
        }
        v2f dz2[8];
#pragma unroll
        for (int i = 0; i < 8; ++i) dz2[i] = {dz[2 * i], dz[2 * i + 1]};

        const v2f cr2 = {cr, cr}, cz2 = {cz, cz};
        const v2f zq2[8] = { {e0.x, e0.y}, {e0.z, e0.w}, {e1.x, e1.y}, {e1.z, e1.w},
                             {e2.x, e2.y}, {e2.z, e2.w}, {e3.x, e3.y}, {e3.z, e3.w} };
#pragma unroll
        for (int i = 0; i < 8; ++i) {
            Zrp[i] = Zrp[i] - cr2 * dz2[i];
            z2[i]  = zq2[i] - cz2 * dz2[i];
        }
        // commit this lane's Ztilde row (off-chain; DS in-order, single wave)
        float4* zw = (float4*)(Z + lane * 20);
        zw[0] = make_float4(Zrp[0].x, Zrp[0].y, Zrp[1].x, Zrp[1].y);
        zw[1] = make_float4(Zrp[2].x, Zrp[2].y, Zrp[3].x, Zrp[3].y);
        zw[2] = make_float4(Zrp[4].x, Zrp[4].y, Zrp[5].x, Zrp[5].y);
        zw[3] = make_float4(Zrp[6].x, Zrp[6].y, Zrp[7].x, Zrp[7].y);

        vv = vnext;
        tk = tkn;
        pairT = pairT1;
        pairT1 = pairT2;
    }

    // ---- final eval: z2 = Ztilde_final[q_token]; ctx = relu(z)@W2_f + b2_f ----
    {
        const v2f zero2 = {0.0f, 0.0f};
        v2f acc = {0.0f, 0.0f};
#pragma unroll
        for (int i = 0; i < 8; ++i)
            acc = acc + __builtin_elementwise_max(z2[i], zero2) * W2p[i];
        ctxbuf[lane] = b2v + acc.x + acc.y;
    }
    __syncthreads();

    float o = outb[lane];
    for (int hh = 0; hh < 64; ++hh) o += ctxbuf[hh] * outw[hh * 64 + lane];
    out[b * 64 + lane] = o;
}

// ---------------- launcher ----------------
extern "C" void kernel_launch(void* const* d_in, const int* in_sizes, int n_in,
                              void* d_out, int out_size, void* d_ws, size_t ws_size,
                              hipStream_t stream) {
    const int*   seq   = (const int*)d_in[0];
    const float* embed = (const float*)d_in[1];
    const float* ffw1  = (const float*)d_in[2];
    const float* ffb1  = (const float*)d_in[3];
    const float* ffw2  = (const float*)d_in[4];
    const float* ffb2  = (const float*)d_in[5];
    const float* lng   = (const float*)d_in[6];
    const float* lnb   = (const float*)d_in[7];
    const float* w1    = (const float*)d_in[8];
    const float* b1    = (const float*)d_in[9];
    const float* w2    = (const float*)d_in[10];
    const float* b2    = (const float*)d_in[11];
    const float* outw  = (const float*)d_in[12];
    const float* outb  = (const float*)d_in[13];
    float* ws  = (float*)d_ws;
    float* out = (float*)d_out;

    hipLaunchKernelGGL(hs_kernel, dim3(64), dim3(128), 0, stream,
                       embed, ffw1, ffb1, ffw2, ffb2, lng, lnb, ws);
    hipLaunchKernelGGL(gz_kernel, dim3(64), dim3(64), 0, stream, w1, b1, ws);
    hipLaunchKernelGGL(ttt_kernel, dim3(256), dim3(64), 0, stream,
                       seq, w2, b2, outw, outb, ws, out);
}

// Round 6
// 539.707 us; speedup vs baseline: 1.2463x; 1.2463x over previous
//
#include <hip/hip_runtime.h>

#define TSTEPS 1023
#define GAMMA  (0.01f / 32.0f)   // LR * dL/dy scale: 2/(64*2) folded
#define EPSV   1e-5f

// workspace layout (float offsets)
#define WS_HS 0       // 64*64 hs table
#define WS_G  4096    // 64*64 gram
#define WS_Z0 8192    // 64*16 initial Ztilde = hs@w1 + b1

typedef float v2f __attribute__((ext_vector_type(2)));
typedef unsigned int v2u __attribute__((ext_vector_type(2)));

template<int CTRL>
__device__ __forceinline__ float dppmov(float x) {
    return __int_as_float(__builtin_amdgcn_update_dpp(0, __float_as_int(x), CTRL, 0xF, 0xF, true));
}
// sum over {l, l^16} / {l, l^32} via permlane swaps (VALU, no DS)
__device__ __forceinline__ float sum_x16(float x) {
    v2u r = __builtin_amdgcn_permlane16_swap(__float_as_uint(x), __float_as_uint(x), false, false);
    return __uint_as_float(r[0]) + __uint_as_float(r[1]);
}
__device__ __forceinline__ float sum_x32(float x) {
    v2u r = __builtin_amdgcn_permlane32_swap(__float_as_uint(x), __float_as_uint(x), false, false);
    return __uint_as_float(r[0]) + __uint_as_float(r[1]);
}

// ---------------- kernel A: hs table (per-token embed->FFN->LN) ----------------
__global__ void hs_kernel(const float* __restrict__ embed,
                          const float* __restrict__ ffw1, const float* __restrict__ ffb1,
                          const float* __restrict__ ffw2, const float* __restrict__ ffb2,
                          const float* __restrict__ lng,  const float* __restrict__ lnb,
                          float* __restrict__ ws) {
    __shared__ float e[64];
    __shared__ float a1[128];
    int w = blockIdx.x;
    int tid = threadIdx.x;
    if (tid < 64) e[tid] = embed[w * 64 + tid];
    __syncthreads();
    float z1 = ffb1[tid];
    for (int x = 0; x < 64; ++x) z1 += e[x] * ffw1[x * 128 + tid];
    a1[tid] = fmaxf(z1, 0.0f);
    __syncthreads();
    if (tid < 64) {
        float f = ffb2[tid];
        for (int i = 0; i < 128; ++i) f += a1[i] * ffw2[i * 64 + tid];
        float hv = e[tid] + f;
        float s = hv;
#pragma unroll
        for (int m = 32; m >= 1; m >>= 1) s += __shfl_xor(s, m);
        float mu = s * (1.0f / 64.0f);
        float dv = hv - mu;
        float vs = dv * dv;
#pragma unroll
        for (int m = 32; m >= 1; m >>= 1) vs += __shfl_xor(vs, m);
        float rstd = 1.0f / sqrtf(vs * (1.0f / 64.0f) + EPSV);
        ws[WS_HS + w * 64 + tid] = dv * rstd * lng[tid] + lnb[tid];
    }
}

// ---------------- kernel B: Gram matrix + Ztilde0 ----------------
__global__ void gz_kernel(const float* __restrict__ w1, const float* __restrict__ b1,
                          float* __restrict__ ws) {
    __shared__ float row[64];
    int w = blockIdx.x, tid = threadIdx.x;
    row[tid] = ws[WS_HS + w * 64 + tid];
    __syncthreads();
    float g = 0.0f;
    for (int x = 0; x < 64; ++x) g += row[x] * ws[WS_HS + tid * 64 + x];
    ws[WS_G + w * 64 + tid] = g;
    if (tid < 16) {
        float z = b1[tid];
        for (int x = 0; x < 64; ++x) z += row[x] * w1[x * 16 + tid];
        ws[WS_Z0 + w * 16 + tid] = z;
    }
}

// scalar view of packed v2f array
#define PV(arr, j) (((j) & 1) ? arr[(j) >> 1].y : arr[(j) >> 1].x)

// ---------------- main kernel: per-batch sequential TTT scan ----------------
// one wave per batch. lane h owns W2[:,h], b2_h, Ztilde row h (regs + LDS
// mirror). All-VALU reduction: keep/give quad_perm folds (xor1,xor2) ->
// row_ror:4/8 orbit sums -> permlane16/32 swap-sums. Mask applied in
// lane-encoded space; broadcast via quad_perm (VGPR-only, no SGPR hazards).
// Last step peeled out of the loop.
__launch_bounds__(64, 1)
__global__ void ttt_kernel(const int* __restrict__ seq,
                           const float* __restrict__ w2, const float* __restrict__ b2i,
                           const float* __restrict__ outw, const float* __restrict__ outb,
                           const float* __restrict__ ws, float* __restrict__ out) {
    __shared__ float hs[64 * 64];
    __shared__ float G[64 * 64];
    __shared__ int   sq[2048];
    __shared__ __align__(16) float Z[64 * 20];   // row stride 20: conflict-free b128
    __shared__ float ctxbuf[64];

    const int b    = blockIdx.x;
    const int lane = threadIdx.x;

    {   // vectorized staging
        float4*       hv = (float4*)hs;
        const float4* sv = (const float4*)(ws + WS_HS);
#pragma unroll
        for (int m = 0; m < 16; ++m) hv[m * 64 + lane] = sv[m * 64 + lane];
        float4*       gv = (float4*)G;
        const float4* gs = (const float4*)(ws + WS_G);
#pragma unroll
        for (int m = 0; m < 16; ++m) gv[m * 64 + lane] = gs[m * 64 + lane];
        int4*       qv = (int4*)sq;
        const int4* qs = (const int4*)(seq + b * 2048);
#pragma unroll
        for (int m = 0; m < 8; ++m) qv[m * 64 + lane] = qs[m * 64 + lane];
    }

    v2f W2p[8], Zrp[8], z2[8];
#pragma unroll
    for (int i = 0; i < 8; ++i) {
        v2f w;
        w.x = w2[(2 * i) * 64 + lane];
        w.y = w2[(2 * i + 1) * 64 + lane];
        W2p[i] = w;
    }
    float b2v = b2i[lane];
    {
        const float4* z0 = (const float4*)(ws + WS_Z0 + lane * 16);
        float4 u0 = z0[0], u1 = z0[1], u2 = z0[2], u3 = z0[3];
        Zrp[0] = {u0.x, u0.y}; Zrp[1] = {u0.z, u0.w};
        Zrp[2] = {u1.x, u1.y}; Zrp[3] = {u1.z, u1.w};
        Zrp[4] = {u2.x, u2.y}; Zrp[5] = {u2.z, u2.w};
        Zrp[6] = {u3.x, u3.y}; Zrp[7] = {u3.z, u3.w};
        float4* zr = (float4*)(Z + lane * 20);
        zr[0] = u0; zr[1] = u1; zr[2] = u2; zr[3] = u3;
    }
    __syncthreads();

    int tk = sq[0];
    {
        const float4* zp = (const float4*)(Z + tk * 20);
        float4 u0 = zp[0], u1 = zp[1], u2 = zp[2], u3 = zp[3];
        z2[0] = {u0.x, u0.y}; z2[1] = {u0.z, u0.w};
        z2[2] = {u1.x, u1.y}; z2[3] = {u1.z, u1.w};
        z2[4] = {u2.x, u2.y}; z2[5] = {u2.z, u2.w};
        z2[6] = {u3.x, u3.y}; z2[7] = {u3.z, u3.w};
    }
    float vv = hs[sq[1] * 64 + lane];

    // token-pair prefetch pipeline (2 ahead)
    int2 pairT  = *(const int2*)(sq + 2);
    int2 pairT1 = *(const int2*)(sq + 4);

    const bool bl0 = (lane & 1) != 0;
    const bool bl1 = (lane & 2) != 0;

    // main loop: steps 0..1021 (last step peeled)
#pragma unroll 2
    for (int t = 0; t < TSTEPS - 1; ++t) {
        const int tkn = pairT.x;
        const int tvn = pairT.y;

        // ---- DS reads issue here with register addresses (consumed late) ----
        const float4* zp = (const float4*)(Z + tkn * 20);   // Ztilde_t[tkn]
        const float4 e0 = zp[0], e1 = zp[1], e2 = zp[2], e3 = zp[3];
        const float vnext = hs[tvn * 64 + lane];
        const float cr = GAMMA * G[tk * 64 + lane] + GAMMA;
        const float cz = GAMMA * G[tk * 64 + tkn] + GAMMA;
        // prefetch for iter t+2 (t=1021 reads sq[2048..2049]: in-LDS garbage, never used)
        const int2 pairT2 = *(const int2*)(sq + 2 * t + 6);

        // ---- forward (packed) ----
        const v2f zero2 = {0.0f, 0.0f};
        v2f a2[8];
#pragma unroll
        for (int i = 0; i < 8; ++i) a2[i] = __builtin_elementwise_max(z2[i], zero2);
        v2f acc0 = a2[0] * W2p[0] + a2[1] * W2p[1];
        v2f acc1 = a2[2] * W2p[2] + a2[3] * W2p[3];
        v2f acc2 = a2[4] * W2p[4] + a2[5] * W2p[5];
        v2f acc3 = a2[6] * W2p[6] + a2[7] * W2p[7];
        v2f accv = (acc0 + acc1) + (acc2 + acc3);
        const float y = b2v + accv.x + accv.y;
        const float d = y - vv;

        // ---- p (pre-update W2) + local W2/b2 update (packed) ----
        const v2f d2 = {d, d};
        v2f p2[8];
#pragma unroll
        for (int i = 0; i < 8; ++i) p2[i] = W2p[i] * d2;
        const float sd = GAMMA * d;
        const v2f sd2 = {sd, sd};
        b2v -= sd;
#pragma unroll
        for (int i = 0; i < 8; ++i) W2p[i] = W2p[i] - sd2 * a2[i];

        // ---- reduction (all-VALU), keep/give folds ----
        float q[8];
#pragma unroll
        for (int j = 0; j < 8; ++j) {
            const float keep = bl0 ? PV(p2, j + 8) : PV(p2, j);
            const float give = bl0 ? PV(p2, j)     : PV(p2, j + 8);
            q[j] = keep + dppmov<0xB1>(give);       // quad_perm [1,0,3,2] (xor1)
        }
        float r[4];
#pragma unroll
        for (int j = 0; j < 4; ++j) {
            const float keep = bl1 ? q[j + 4] : q[j];
            const float give = bl1 ? q[j]     : q[j + 4];
            r[j] = keep + dppmov<0x4E>(give);       // quad_perm [2,3,0,1] (xor2)
        }
        float tot[4];
#pragma unroll
        for (int j = 0; j < 4; ++j) {
            float x = r[j] + dppmov<0x124>(r[j]);   // row_ror:4
            x = x + dppmov<0x128>(x);               // row_ror:8
            x = sum_x16(x);
            tot[j] = sum_x32(x);
        }
        // tot[jj] = da[jj + 4*b1 + 8*b0] in EVERY lane (replicated across quads)

        // ---- mask in encoded space, then quad_perm broadcast ----
        float totm[4];
#pragma unroll
        for (int jj = 0; jj < 4; ++jj) {
            const float s0 = bl1 ? PV(a2, jj + 4)  : PV(a2, jj);      // b0=0: a[jj+4*b1]
            const float s1 = bl1 ? PV(a2, jj + 12) : PV(a2, jj + 8);  // b0=1
            const float aenc = bl0 ? s1 : s0;
            totm[jj] = (aenc > 0.0f) ? tot[jj] : 0.0f;                // = dz encoded
        }
        // dz[m] uniform: quad_perm broadcast from quad position p = (m>>3) + 2*((m>>2)&1)
        float dz[16];
        dz[0]  = dppmov<0x00>(totm[0]);  dz[1]  = dppmov<0x00>(totm[1]);
        dz[2]  = dppmov<0x00>(totm[2]);  dz[3]  = dppmov<0x00>(totm[3]);
        dz[4]  = dppmov<0xAA>(totm[0]);  dz[5]  = dppmov<0xAA>(totm[1]);
        dz[6]  = dppmov<0xAA>(totm[2]);  dz[7]  = dppmov<0xAA>(totm[3]);
        dz[8]  = dppmov<0x55>(totm[0]);  dz[9]  = dppmov<0x55>(totm[1]);
        dz[10] = dppmov<0x55>(totm[2]);  dz[11] = dppmov<0x55>(totm[3]);
        dz[12] = dppmov<0xFF>(totm[0]);  dz[13] = dppmov<0xFF>(totm[1]);
        dz[14] = dppmov<0xFF>(totm[2]);  dz[15] = dppmov<0xFF>(totm[3]);

        v2f dz2[8];
#pragma unroll
        for (int i = 0; i < 8; ++i) dz2[i] = {dz[2 * i], dz[2 * i + 1]};

        // ---- apply + writeback ----
        const v2f cr2 = {cr, cr}, cz2 = {cz, cz};
        const v2f zq2[8] = { {e0.x, e0.y}, {e0.z, e0.w}, {e1.x, e1.y}, {e1.z, e1.w},
                             {e2.x, e2.y}, {e2.z, e2.w}, {e3.x, e3.y}, {e3.z, e3.w} };
#pragma unroll
        for (int i = 0; i < 8; ++i) {
            Zrp[i] = Zrp[i] - cr2 * dz2[i];
            z2[i]  = zq2[i] - cz2 * dz2[i];
        }
        float4* zw = (float4*)(Z + lane * 20);
        zw[0] = make_float4(Zrp[0].x, Zrp[0].y, Zrp[1].x, Zrp[1].y);
        zw[1] = make_float4(Zrp[2].x, Zrp[2].y, Zrp[3].x, Zrp[3].y);
        zw[2] = make_float4(Zrp[4].x, Zrp[4].y, Zrp[5].x, Zrp[5].y);
        zw[3] = make_float4(Zrp[6].x, Zrp[6].y, Zrp[7].x, Zrp[7].y);

        vv = vnext;
        tk = tkn;
        pairT = pairT1;
        pairT1 = pairT2;
    }

    // ---- peeled final step (t = 1022): tkn = query token sq[2047]; no Zr/writeback ----
    {
        const int tkn = pairT.y;                    // pairT = {sq[2046], sq[2047]}
        const float4* zp = (const float4*)(Z + tkn * 20);
        const float4 e0 = zp[0], e1 = zp[1], e2 = zp[2], e3 = zp[3];
        const float cz = GAMMA * G[tk * 64 + tkn] + GAMMA;

        const v2f zero2 = {0.0f, 0.0f};
        v2f a2[8];
#pragma unroll
        for (int i = 0; i < 8; ++i) a2[i] = __builtin_elementwise_max(z2[i], zero2);
        v2f acc0 = a2[0] * W2p[0] + a2[1] * W2p[1];
        v2f acc1 = a2[2] * W2p[2] + a2[3] * W2p[3];
        v2f acc2 = a2[4] * W2p[4] + a2[5] * W2p[5];
        v2f acc3 = a2[6] * W2p[6] + a2[7] * W2p[7];
        v2f accv = (acc0 + acc1) + (acc2 + acc3);
        const float y = b2v + accv.x + accv.y;
        const float d = y - vv;

        const v2f d2 = {d, d};
        v2f p2[8];
#pragma unroll
        for (int i = 0; i < 8; ++i) p2[i] = W2p[i] * d2;
        const float sd = GAMMA * d;
        const v2f sd2 = {sd, sd};
        b2v -= sd;
#pragma unroll
        for (int i = 0; i < 8; ++i) W2p[i] = W2p[i] - sd2 * a2[i];

        float q[8];
#pragma unroll
        for (int j = 0; j < 8; ++j) {
            const float keep = bl0 ? PV(p2, j + 8) : PV(p2, j);
            const float give = bl0 ? PV(p2, j)     : PV(p2, j + 8);
            q[j] = keep + dppmov<0xB1>(give);
        }
        float r[4];
#pragma unroll
        for (int j = 0; j < 4; ++j) {
            const float keep = bl1 ? q[j + 4] : q[j];
            const float give = bl1 ? q[j]     : q[j + 4];
            r[j] = keep + dppmov<0x4E>(give);
        }
        float tot[4];
#pragma unroll
        for (int j = 0; j < 4; ++j) {
            float x = r[j] + dppmov<0x124>(r[j]);
            x = x + dppmov<0x128>(x);
            x = sum_x16(x);
            tot[j] = sum_x32(x);
        }
        float totm[4];
#pragma unroll
        for (int jj = 0; jj < 4; ++jj) {
            const float s0 = bl1 ? PV(a2, jj + 4)  : PV(a2, jj);
            const float s1 = bl1 ? PV(a2, jj + 12) : PV(a2, jj + 8);
            const float aenc = bl0 ? s1 : s0;
            totm[jj] = (aenc > 0.0f) ? tot[jj] : 0.0f;
        }
        float dz[16];
        dz[0]  = dppmov<0x00>(totm[0]);  dz[1]  = dppmov<0x00>(totm[1]);
        dz[2]  = dppmov<0x00>(totm[2]);  dz[3]  = dppmov<0x00>(totm[3]);
        dz[4]  = dppmov<0xAA>(totm[0]);  dz[5]  = dppmov<0xAA>(totm[1]);
        dz[6]  = dppmov<0xAA>(totm[2]);  dz[7]  = dppmov<0xAA>(totm[3]);
        dz[8]  = dppmov<0x55>(totm[0]);  dz[9]  = dppmov<0x55>(totm[1]);
        dz[10] = dppmov<0x55>(totm[2]);  dz[11] = dppmov<0x55>(totm[3]);
        dz[12] = dppmov<0xFF>(totm[0]);  dz[13] = dppmov<0xFF>(totm[1]);
        dz[14] = dppmov<0xFF>(totm[2]);  dz[15] = dppmov<0xFF>(totm[3]);

        const v2f cz2 = {cz, cz};
        const v2f zq2[8] = { {e0.x, e0.y}, {e0.z, e0.w}, {e1.x, e1.y}, {e1.z, e1.w},
                             {e2.x, e2.y}, {e2.z, e2.w}, {e3.x, e3.y}, {e3.z, e3.w} };
#pragma unroll
        for (int i = 0; i < 8; ++i) {
            v2f dzi = {dz[2 * i], dz[2 * i + 1]};
            z2[i] = zq2[i] - cz2 * dzi;
        }
    }

    // ---- final eval: ctx = relu(z_final)@W2_f + b2_f ----
    {
        const v2f zero2 = {0.0f, 0.0f};
        v2f acc = {0.0f, 0.0f};
#pragma unroll
        for (int i = 0; i < 8; ++i)
            acc = acc + __builtin_elementwise_max(z2[i], zero2) * W2p[i];
        ctxbuf[lane] = b2v + acc.x + acc.y;
    }
    __syncthreads();

    float o = outb[lane];
    for (int hh = 0; hh < 64; ++hh) o += ctxbuf[hh] * outw[hh * 64 + lane];
    out[b * 64 + lane] = o;
}

// ---------------- launcher ----------------
extern "C" void kernel_launch(void* const* d_in, const int* in_sizes, int n_in,
                              void* d_out, int out_size, void* d_ws, size_t ws_size,
                              hipStream_t stream) {
    const int*   seq   = (const int*)d_in[0];
    const float* embed = (const float*)d_in[1];
    const float* ffw1  = (const float*)d_in[2];
    const float* ffb1  = (const float*)d_in[3];
    const float* ffw2  = (const float*)d_in[4];
    const float* ffb2  = (const float*)d_in[5];
    const float* lng   = (const float*)d_in[6];
    const float* lnb   = (const float*)d_in[7];
    const float* w1    = (const float*)d_in[8];
    const float* b1    = (const float*)d_in[9];
    const float* w2    = (const float*)d_in[10];
    const float* b2    = (const float*)d_in[11];
    const float* outw  = (const float*)d_in[12];
    const float* outb  = (const float*)d_in[13];
    float* ws  = (float*)d_ws;
    float* out = (float*)d_out;

    hipLaunchKernelGGL(hs_kernel, dim3(64), dim3(128), 0, stream,
                       embed, ffw1, ffb1, ffw2, ffb2, lng, lnb, ws);
    hipLaunchKernelGGL(gz_kernel, dim3(64), dim3(64), 0, stream, w1, b1, ws);
    hipLaunchKernelGGL(ttt_kernel, dim3(256), dim3(64), 0, stream,
                       seq, w2, b2, outw, outb, ws, out);
}